// Round 9
// baseline (537.218 us; speedup 1.0000x reference)
//
#include <hip/hip_runtime.h>
#include <math.h>

// ---------------------------------------------------------------------------
// InfoNCE on MI355X — v12.
// Single-kernel fusion WITHOUT cooperative launch. v11's hipLaunchCooperative-
// Kernel never dispatched (output==memset 0, absmax == |ref| == 1.15e-3, no
// rocprof rows) -> replaced by a deadlock-free software pipeline in one plain
// launch:
//   phase0: prep units (1536) claimed by atomic TICKET (work-stealing: any
//     resident subset of blocks drains all tickets; no cross-block wait on
//     unscheduled work). Release = syncthreads (drains stores to L2) + one
//     __threadfence (buffer_wbl2, cross-XCD writeback) + atomicAdd(done,n).
//     All blocks spin (s_sleep) until done==1536, then acquire-fence.
//   phase1: v9's validated pair body (M-tile 64, 8 waves, wave 64x64,
//     barrier-free K-loop, 2 MFMA products, 66.5 KB LDS) grid-strided over
//     4096 tiles + v10's validated atomic epilogue (diag->t0g, row exp-sums
//     -> atomicAdd(rsm)).
//   phase2: last-block-does-reduction (rank via atomic; rank GRID-1 reduces
//     t0g/log(rsm) -> out).
// Rationale: v8/v9/v10 all show ~90-100 us of inter-kernel launch gaps
// (total - pair - ~30 us device work), bigger than any utilization delta
// actually banked across five structural experiments (all pinned 37-43%).
// ---------------------------------------------------------------------------

typedef __bf16 bf16x8 __attribute__((ext_vector_type(8)));
typedef float  f32x16 __attribute__((ext_vector_type(16)));

#define H      512
#define NPTS   512
#define XD     128
#define SPA    520   // A-tile LDS row stride (elems): 1040 B (0 conflicts)
#define PLS    12    // epilogue partial-scratch row stride (f32)
#define GRID   512
#define NTILE  4096  // 64 i-groups x 64 j-groups (M-tile 64 = 8i x 8j)
#define NUNITS 1536  // 1024 hx/hy rows + 512 W2 repack cols

__global__ __launch_bounds__(512, 4) void fused_kernel(
    const float* __restrict__ x, const float* __restrict__ y,
    const float* __restrict__ W1x, const float* __restrict__ W1y,
    const float* __restrict__ b1, const float* __restrict__ W2,
    const float* __restrict__ b2, const float* __restrict__ W3,
    const float* __restrict__ b3,
    float* __restrict__ hx, float* __restrict__ hy,
    __bf16* __restrict__ w2h, __bf16* __restrict__ w2l,
    float* __restrict__ t0g, float* __restrict__ rsm,
    int* __restrict__ ctl, float* __restrict__ out) {
  extern __shared__ __align__(16) __bf16 Ah[];   // [64][SPA] = 66560 B
  __shared__ float xr[XD];
  __shared__ float s1[8], s2[8];
  __shared__ int sbc;

  const int t    = threadIdx.x;
  const int wave = t >> 6;
  const int lane = t & 63;

  // ================= phase 0: ticket-claimed prep ======================
  // unit u < 1024: one hx/hy row (512 cols, 1 col/thread).
  // unit u >= 1024: one W2 column n -> fragment-major bf16 hi/lo (k = t).
  int my = 0;
  for (;;) {
    if (t == 0) sbc = atomicAdd(ctl + 0, 1);
    __syncthreads();
    const int u = sbc;
    if (u >= NUNITS) break;
    if (u < 2 * NPTS) {
      const bool isY = (u >= NPTS);
      const int row = isY ? u - NPTS : u;
      const float* src = isY ? y : x;      // [NPTS][XD]
      const float* W   = isY ? W1y : W1x;  // [XD][H]
      if (t < XD) xr[t] = src[row * XD + t];
      __syncthreads();
      float s = 0.f;
#pragma unroll
      for (int k = 0; k < XD; ++k) s = fmaf(xr[k], W[k * H + t], s);
      if (isY) hy[row * H + t] = s + b1[t];   // fold b1 into hy
      else     hx[row * H + t] = s;
    } else {
      // idx = ((n>>5)*32 + (k>>4))*512 + (n&31)*16 + (k&15), k = t
      const int n = u - 2 * NPTS;
      const float v = W2[t * H + n];
      __bf16 hi = (__bf16)v;
      float lo = v - (float)hi;
      const int idx = (((n >> 5) * 32) + (t >> 4)) * 512 + (n & 31) * 16 + (t & 15);
      w2h[idx] = hi;
      w2l[idx] = (__bf16)lo;
    }
    ++my;
    __syncthreads();   // xr reads done before next unit overwrites
  }
  // release this block's units, then wait for all 1536
  if (t == 0) {
    if (my) { __threadfence(); atomicAdd(ctl + 1, my); }
    while (__hip_atomic_load(ctl + 1, __ATOMIC_RELAXED,
                             __HIP_MEMORY_SCOPE_AGENT) < NUNITS)
      __builtin_amdgcn_s_sleep(8);
  }
  __syncthreads();
  __threadfence();   // acquire: invalidate stale lines before reading prep out

  // ================= phase 1: pair tiles (grid-stride) =================
  const int r31  = lane & 31;
  const int half = lane >> 5;
  const int boff = r31 * 16 + half * 8;
  const __bf16* w2hW = w2h + wave * 32768 + boff;
  const __bf16* w2lW = w2l + wave * 32768 + boff;
  const float bb0 = b2[wave * 64 + r31];
  const float bb1 = b2[wave * 64 + 32 + r31];
  const float w30 = W3[wave * 64 + r31];
  const float w31 = W3[wave * 64 + 32 + r31];

  for (int tile = blockIdx.x; tile < NTILE; tile += GRID) {
    const int i0 = (tile >> 6) * 8;
    const int j0 = (tile & 63) * 8;

    // B loads for half-step 0 (issued before staging; land during it)
    bf16x8 Bh[2][2], Bl[2][2];
    Bh[0][0] = *(const bf16x8*)(w2hW);
    Bh[0][1] = *(const bf16x8*)(w2hW + 16384);
    Bl[0][0] = *(const bf16x8*)(w2lW);
    Bl[0][1] = *(const bf16x8*)(w2lW + 16384);

    // ---- stage the whole 64 x 512 A tile (8 thr/row, 8 segs/thr) ----
    {
      const int sm = t >> 3;        // pair row 0..63 (ti = sm>>3, tj = sm&7)
      const int sl = t & 7;
      const float* hxp = hx + (j0 + (sm & 7)) * H;
      const float* hyp = hy + (i0 + (sm >> 3)) * H;
      __bf16* arow = Ah + sm * SPA;
#pragma unroll
      for (int c = 0; c < 8; ++c) {
        const int k = sl * 8 + c * 64;
        float4 x0 = *(const float4*)(hxp + k);
        float4 x1 = *(const float4*)(hxp + k + 4);
        float4 y0 = *(const float4*)(hyp + k);
        float4 y1 = *(const float4*)(hyp + k + 4);
        float a[8] = {x0.x + y0.x, x0.y + y0.y, x0.z + y0.z, x0.w + y0.w,
                      x1.x + y1.x, x1.y + y1.y, x1.z + y1.z, x1.w + y1.w};
        bf16x8 hv;
#pragma unroll
        for (int e = 0; e < 8; ++e) {
          float v = a[e] > 0.f ? a[e] : 0.f;   // first relu
          hv[e] = (__bf16)v;
        }
        *(bf16x8*)(&arow[k]) = hv;
      }
    }

    f32x16 acc[2][2] = {};
    __syncthreads();   // staging complete

    // walking pointers (only per-iter address state: +512 / +16 elems)
    const __bf16* pBh = w2hW;
    const __bf16* pBl = w2lW;
    const __bf16* pA  = Ah + r31 * SPA + half * 8;

    bf16x8 Ab[2][2];
    Ab[0][0] = *(const bf16x8*)(pA);
    Ab[0][1] = *(const bf16x8*)(pA + 32 * SPA);

    // ---- barrier-free K-loop: 32 half-steps of K=16 ----
#pragma unroll 2
    for (int hs = 0; hs < 32; ++hs) {
      const int cur = hs & 1;
      if (hs < 31) {   // prefetch B and A for next half-step
        Bh[cur ^ 1][0] = *(const bf16x8*)(pBh + 512);
        Bh[cur ^ 1][1] = *(const bf16x8*)(pBh + 16384 + 512);
        Bl[cur ^ 1][0] = *(const bf16x8*)(pBl + 512);
        Bl[cur ^ 1][1] = *(const bf16x8*)(pBl + 16384 + 512);
        Ab[cur ^ 1][0] = *(const bf16x8*)(pA + 16);
        Ab[cur ^ 1][1] = *(const bf16x8*)(pA + 32 * SPA + 16);
        pBh += 512; pBl += 512; pA += 16;
      }
      __builtin_amdgcn_s_setprio(1);
      acc[0][0] = __builtin_amdgcn_mfma_f32_32x32x16_bf16(Ab[cur][0], Bh[cur][0], acc[0][0], 0, 0, 0);
      acc[0][1] = __builtin_amdgcn_mfma_f32_32x32x16_bf16(Ab[cur][0], Bh[cur][1], acc[0][1], 0, 0, 0);
      acc[1][0] = __builtin_amdgcn_mfma_f32_32x32x16_bf16(Ab[cur][1], Bh[cur][0], acc[1][0], 0, 0, 0);
      acc[1][1] = __builtin_amdgcn_mfma_f32_32x32x16_bf16(Ab[cur][1], Bh[cur][1], acc[1][1], 0, 0, 0);
      acc[0][0] = __builtin_amdgcn_mfma_f32_32x32x16_bf16(Ab[cur][0], Bl[cur][0], acc[0][0], 0, 0, 0);
      acc[0][1] = __builtin_amdgcn_mfma_f32_32x32x16_bf16(Ab[cur][0], Bl[cur][1], acc[0][1], 0, 0, 0);
      acc[1][0] = __builtin_amdgcn_mfma_f32_32x32x16_bf16(Ab[cur][1], Bl[cur][0], acc[1][0], 0, 0, 0);
      acc[1][1] = __builtin_amdgcn_mfma_f32_32x32x16_bf16(Ab[cur][1], Bl[cur][1], acc[1][1], 0, 0, 0);
      __builtin_amdgcn_s_setprio(0);
    }

    __syncthreads();   // all waves done reading Ah -> safe to alias

    // ---- epilogue: relu(h2+b2)*W3, shfl-reduce, softplus, row sums ----
    float* PL = (float*)Ah;          // [64][PLS], aliases dead A tile
#pragma unroll
    for (int mt = 0; mt < 2; ++mt) {
#pragma unroll
      for (int r = 0; r < 16; ++r) {
        float v0 = acc[mt][0][r] + bb0;
        float v1 = acc[mt][1][r] + bb1;
        v0 = v0 > 0.f ? v0 : 0.f;          // second relu
        v1 = v1 > 0.f ? v1 : 0.f;
        float p = fmaf(v0, w30, v1 * w31);
        p += __shfl_xor(p, 1);
        p += __shfl_xor(p, 2);
        p += __shfl_xor(p, 4);
        p += __shfl_xor(p, 8);
        p += __shfl_xor(p, 16);
        if (r31 == 0) {
          const int row = mt * 32 + (r & 3) + 8 * (r >> 2) + 4 * half;
          PL[row * PLS + wave] = p;
        }
      }
    }
    __syncthreads();
    if (t < 64) {
      float4 q0 = *(const float4*)(PL + t * PLS);
      float4 q1 = *(const float4*)(PL + t * PLS + 4);
      float s = b3[0] + q0.x + q0.y + q0.z + q0.w + q1.x + q1.y + q1.z + q1.w;
      const float sp = s > 0.f ? s + log1pf(expf(-s)) : log1pf(expf(s));
      const int ti = t >> 3, tj = t & 7;
      const int gi = i0 + ti, gj = j0 + tj;
      if (gi == gj) t0g[gi] = sp;          // diag == T0, written exactly once
      float e = expf(sp);
      e += __shfl_xor(e, 1);               // sum over this tile's 8 j's
      e += __shfl_xor(e, 2);
      e += __shfl_xor(e, 4);
      if (tj == 0) atomicAdd(rsm + gi, e);
    }
    __syncthreads();   // PL consumed before next tile's staging
  }

  // ================= phase 2: last block reduces =======================
  if (t == 0) { __threadfence(); sbc = atomicAdd(ctl + 2, 1); }
  __syncthreads();
  if (sbc == GRID - 1) {
    __threadfence();   // acquire: see every block's t0g stores + rsm adds
    float a = t0g[t];
    float l = logf(rsm[t]);
#pragma unroll
    for (int off = 1; off < 64; off <<= 1) {
      a += __shfl_xor(a, off);
      l += __shfl_xor(l, off);
    }
    if (lane == 0) { s1[wave] = a; s2[wave] = l; }
    __syncthreads();
    if (t == 0) {
      float sa = 0.f, sb = 0.f;
#pragma unroll
      for (int i = 0; i < 8; ++i) { sa += s1[i]; sb += s2[i]; }
      out[0] = sa / 512.0f - sb / 512.0f + logf(512.0f);
    }
  }
}

// ---------------------------------------------------------------------------
extern "C" void kernel_launch(void* const* d_in, const int* in_sizes, int n_in,
                              void* d_out, int out_size, void* d_ws, size_t ws_size,
                              hipStream_t stream) {
  const float* x   = (const float*)d_in[0];
  const float* y   = (const float*)d_in[1];
  const float* W1x = (const float*)d_in[2];
  const float* W1y = (const float*)d_in[3];
  const float* b1  = (const float*)d_in[4];
  const float* W2  = (const float*)d_in[5];
  const float* b2  = (const float*)d_in[6];
  const float* W3  = (const float*)d_in[7];
  const float* b3  = (const float*)d_in[8];

  float* ws = (float*)d_ws;
  float* hx  = ws;                        // 512*512 f32
  float* hy  = ws + 262144;               // 512*512 f32
  float* t0g = ws + 524288;               // 512 f32 (diag = T0)
  float* rsm = ws + 524288 + 512;         // 512 f32 (row exp-sums)
  int*   ctl = (int*)(ws + 524288 + 1024);// control: 0 ticket, 1 done, 2 rank
  __bf16* w2h = (__bf16*)(ws + 786432);   // 512*512 bf16 (fragment-major)
  __bf16* w2l = w2h + 262144;             // 512*512 bf16
  float* out = (float*)d_out;

  static bool configured = false;
  if (!configured) {
    hipFuncSetAttribute(reinterpret_cast<const void*>(fused_kernel),
                        hipFuncAttributeMaxDynamicSharedMemorySize,
                        64 * SPA * 2);
    configured = true;
  }

  // zero rsm + ctl (2048 B + 64 B, contiguous)
  hipMemsetAsync(rsm, 0, 512 * sizeof(float) + 64, stream);
  hipLaunchKernelGGL(fused_kernel, dim3(GRID), dim3(512), 64 * SPA * 2, stream,
                     x, y, W1x, W1y, b1, W2, b2, W3, b3,
                     hx, hy, w2h, w2l, t0g, rsm, ctl, out);
}